// Round 3
// baseline (40.868 us; speedup 1.0000x reference)
//
#include <hip/hip_runtime.h>

#define HH 96
#define WW 96
#define NPX (HH*WW)         // 9216
#define HID 16
#define OUTC 10
#define TT 8
#define BB 2
#define BETA 0.9f

#define THREADS 128
#define NBLK (BB*HH)        // 192

// ws float layout:
//  ws[0]            : block-completion counter (uint), zeroed via hipMemsetAsync per call
//  [CNT_BASE .. )   : count partials, ws[CNT_BASE + (t*16+d)*NBLK + blk]  (waves pre-combined)
//  [SM_BASE  .. )   : smooth partials, ws[SM_BASE + blk]
#define CNT_BASE 64
#define CNT_FLOATS (TT*HID*NBLK)     // 24576
#define SM_BASE (CNT_BASE + CNT_FLOATS)
#define DENOM 2359296.0f             // T*B*N*HID

// z (no bias) for one pixel's x, 4 channels of this thread's channel group
__device__ __forceinline__ float4 proj4(const float4 xv,
                                        const float* __restrict__ w0,
                                        const float* __restrict__ w1,
                                        const float* __restrict__ w2)
{
  float4 r;
  r.x = fmaf(xv.z, w2[0], fmaf(xv.y, w1[0], xv.x*w0[0]));
  r.y = fmaf(xv.z, w2[1], fmaf(xv.y, w1[1], xv.x*w0[1]));
  r.z = fmaf(xv.z, w2[2], fmaf(xv.y, w1[2], xv.x*w0[2]));
  r.w = fmaf(xv.z, w2[3], fmaf(xv.y, w1[3], xv.x*w0[3]));
  return r;
}

__global__ __launch_bounds__(THREADS)
void snn_fused(const float* __restrict__ x,
               const float* __restrict__ wproj,
               const float* __restrict__ bproj,
               const float* __restrict__ whead,
               const float* __restrict__ bhead,
               float* __restrict__ ws,
               float* __restrict__ out)
{
  __shared__ float4 xbuf[TT*3*WW];     // 36864 B: [t][g][col], .w = pad
  __shared__ float4 cbuf[WW*4];        // 6144 B: vertical 3-sums [col][cg]
  __shared__ float4 cntslot[TT][2][4]; // per-t per-wave spike counts (lanes 0..3 = cg)
  __shared__ float  smslot[2];
  __shared__ float  redslot[4];
  __shared__ int    lastflag;
  __shared__ float  cnt_s[TT][BB][HID];
  __shared__ float  log_s[TT*BB*OUTC];

  const int row  = blockIdx.x;    // 0..95
  const int b    = blockIdx.y;    // 0..1
  const int blk  = b*HH + row;
  const int tid  = threadIdx.x;
  const int lane = tid & 63;
  const int wv   = tid >> 6;
  const int cg   = tid & 3;       // channel group (4 channels)
  const int pbase= tid >> 2;      // 0..31

  // per-thread projection weights for this channel group
  float w0[4], w1[4], w2[4], bp[4];
#pragma unroll
  for (int j = 0; j < 4; ++j) {
    w0[j] = wproj[0*HID + cg*4 + j];
    w1[j] = wproj[1*HID + cg*4 + j];
    w2[j] = wproj[2*HID + cg*4 + j];
    bp[j] = bproj[cg*4 + j];
  }

  // ---- prologue: stage ALL x this block ever needs into LDS (once) ----
  // 2304 pixels = 8t x 3rows x 96cols, 18 per thread, padded to float4
#pragma unroll
  for (int i = 0; i < 18; ++i) {
    int p   = tid + THREADS*i;          // 0..2303
    int t   = p / 288;
    int rem = p - t*288;
    int g   = rem / 96;
    int col = rem - g*96;
    int rr  = row + g - 1;
    rr = (rr < 0) ? rr + HH : (rr >= HH ? rr - HH : rr);
    const float* xp = x + ((size_t)(t*BB + b)*NPX + (size_t)rr*WW + col)*3;
    xbuf[t*288 + g*96 + col] = make_float4(xp[0], xp[1], xp[2], 0.f);
  }
  __syncthreads();

  float4 v[3];
#pragma unroll
  for (int k = 0; k < 3; ++k) v[k] = make_float4(0.f,0.f,0.f,0.f);
  float smooth_acc = 0.f;
  const float inv9 = 1.0f/9.0f;

  for (int t = 0; t < TT; ++t) {
    // ---- phase 1: vertical 3-sum of z on core row (z recomputed from LDS x) ----
    float4 zc[3];
#pragma unroll
    for (int k = 0; k < 3; ++k) {
      int col = pbase + 32*k;
      float4 xm = xbuf[t*288 +        col];
      float4 x0 = xbuf[t*288 +  96 +  col];
      float4 xq = xbuf[t*288 + 192 +  col];
      float4 zm = proj4(xm, w0, w1, w2);
      float4 z0 = proj4(x0, w0, w1, w2);
      float4 zq = proj4(xq, w0, w1, w2);
      zc[k] = z0;                         // core z (bias added later)
      float4 c;
      c.x = zm.x + z0.x + zq.x;
      c.y = zm.y + z0.y + zq.y;
      c.z = zm.z + z0.z + zq.z;
      c.w = zm.w + z0.w + zq.w;
      cbuf[col*4 + cg] = c;
    }
    __syncthreads();

    // ---- phase 2: horizontal 3-sum -> agg; LIF; reductions ----
    float4 cnt = make_float4(0.f,0.f,0.f,0.f);
#pragma unroll
    for (int k = 0; k < 3; ++k) {
      int col = pbase + 32*k;
      int cl = (col == 0)    ? (WW-1) : (col-1);
      int cr = (col == WW-1) ? 0      : (col+1);
      float4 s0 = cbuf[cl*4 + cg];
      float4 s1 = cbuf[col*4 + cg];
      float4 s2 = cbuf[cr*4 + cg];
      float gx = (s0.x + s1.x + s2.x) * inv9;   // agg minus bias
      float gy = (s0.y + s1.y + s2.y) * inv9;
      float gz = (s0.z + s1.z + s2.z) * inv9;
      float gw = (s0.w + s1.w + s2.w) * inv9;
      smooth_acc += fabsf(gx - zc[k].x);        // bias cancels in agg - z
      smooth_acc += fabsf(gy - zc[k].y);
      smooth_acc += fabsf(gz - zc[k].z);
      smooth_acc += fabsf(gw - zc[k].w);
      float vx = fmaf(BETA, v[k].x, gx + bp[0]);
      float vy = fmaf(BETA, v[k].y, gy + bp[1]);
      float vz = fmaf(BETA, v[k].z, gz + bp[2]);
      float vw = fmaf(BETA, v[k].w, gw + bp[3]);
      float sx = (vx > 1.0f) ? 1.0f : 0.0f;
      float sy = (vy > 1.0f) ? 1.0f : 0.0f;
      float sz = (vz > 1.0f) ? 1.0f : 0.0f;
      float sw = (vw > 1.0f) ? 1.0f : 0.0f;
      cnt.x += sx; cnt.y += sy; cnt.z += sz; cnt.w += sw;
      v[k].x = vx - sx;
      v[k].y = vy - sy;
      v[k].z = vz - sz;
      v[k].w = vw - sw;
    }

    // reduce cnt over lanes sharing (lane&3); lanes 0..3 hold cg 0..3
#pragma unroll
    for (int off = 4; off < 64; off <<= 1) {
      cnt.x += __shfl_xor(cnt.x, off);
      cnt.y += __shfl_xor(cnt.y, off);
      cnt.z += __shfl_xor(cnt.z, off);
      cnt.w += __shfl_xor(cnt.w, off);
    }
    if (lane < 4) cntslot[t][wv][lane] = cnt;
    __syncthreads();    // protects cbuf for next iteration's phase-1 writes
  }

  // ---- per-block epilogue: combine waves, publish partials ----
#pragma unroll
  for (int off = 1; off < 64; off <<= 1)
    smooth_acc += __shfl_xor(smooth_acc, off);
  if (lane == 0) smslot[wv] = smooth_acc;
  __syncthreads();

  if (tid < 32) {                 // one (t, cg) each
    int t = tid >> 2, c4 = tid & 3;
    float4 a = cntslot[t][0][c4];
    float4 bq = cntslot[t][1][c4];
    float tot[4] = { a.x+bq.x, a.y+bq.y, a.z+bq.z, a.w+bq.w };
#pragma unroll
    for (int comp = 0; comp < 4; ++comp)
      ws[CNT_BASE + (t*HID + c4*4 + comp)*NBLK + blk] = tot[comp];
  }
  if (tid == 0) ws[SM_BASE + blk] = smslot[0] + smslot[1];

  // ---- last-block finalize ----
  __threadfence();                               // release partials
  if (tid == 0)
    lastflag = (atomicAdd((unsigned int*)ws, 1u) == NBLK-1u);
  __syncthreads();
  if (!lastflag) return;
  __threadfence();                               // acquire all partials

  // counts: 128 slots (t*16+d), each summing 192 contiguous floats (96 per batch)
  {
    const float4* src = (const float4*)(ws + CNT_BASE + tid*NBLK);
    float s0 = 0.f, s1 = 0.f;
#pragma unroll 8
    for (int q = 0; q < 24; ++q) { float4 a = src[q];    s0 += a.x+a.y+a.z+a.w; }
#pragma unroll 8
    for (int q = 24; q < 48; ++q){ float4 a = src[q];    s1 += a.x+a.y+a.z+a.w; }
    int t = tid >> 4, d = tid & 15;
    cnt_s[t][0][d] = s0;
    cnt_s[t][1][d] = s1;
  }
  __syncthreads();

  // logits_seq
  for (int i = tid; i < TT*BB*OUTC; i += THREADS) {
    int t = i / (BB*OUTC);
    int r = i - t*(BB*OUTC);
    int bq = r / OUTC;
    int o  = r - bq*OUTC;
    float acc = bhead[o];
#pragma unroll
    for (int d = 0; d < HID; ++d)
      acc = fmaf(cnt_s[t][bq][d] * (1.0f/9216.0f), whead[d*OUTC + o], acc);
    log_s[i] = acc;
    out[20 + i] = acc;
  }
  __syncthreads();

  if (tid < BB*OUTC) {            // time-mean readout
    int bq = tid / OUTC, o = tid - bq*OUTC;
    float a = 0.f;
#pragma unroll
    for (int t = 0; t < TT; ++t) a += log_s[(t*BB + bq)*OUTC + o];
    out[tid] = a * (1.0f/TT);
  }

  // sr and smooth, wave-parallel
  {
    float s_sr = (&cnt_s[0][0][0])[tid] + (&cnt_s[0][0][0])[tid + 128];
    float s_sm = ws[SM_BASE + tid] + ((tid < NBLK-THREADS) ? ws[SM_BASE + THREADS + tid] : 0.f);
#pragma unroll
    for (int off = 1; off < 64; off <<= 1) {
      s_sr += __shfl_xor(s_sr, off);
      s_sm += __shfl_xor(s_sm, off);
    }
    if (lane == 0) { redslot[wv] = s_sr; redslot[2+wv] = s_sm; }
    __syncthreads();
    if (tid == 0) {
      out[180] = (redslot[0] + redslot[1]) / DENOM;
      out[181] = (redslot[2] + redslot[3]) / DENOM;
    }
  }
}

extern "C" void kernel_launch(void* const* d_in, const int* in_sizes, int n_in,
                              void* d_out, int out_size, void* d_ws, size_t ws_size,
                              hipStream_t stream)
{
  const float* x     = (const float*)d_in[0];
  const float* wproj = (const float*)d_in[1];
  const float* bproj = (const float*)d_in[2];
  const float* whead = (const float*)d_in[3];
  const float* bhead = (const float*)d_in[4];
  float* out = (float*)d_out;
  float* ws  = (float*)d_ws;

  (void)hipMemsetAsync(ws, 0, 4, stream);   // zero the completion counter (graph-capturable)
  dim3 grid(HH, BB);
  snn_fused<<<grid, dim3(THREADS), 0, stream>>>(x, wproj, bproj, whead, bhead, ws, out);
}

// Round 4
// 21.528 us; speedup vs baseline: 1.8984x; 1.8984x over previous
//
#include <hip/hip_runtime.h>

#define HH 96
#define WW 96
#define NPX (HH*WW)         // 9216
#define HID 16
#define OUTC 10
#define TT 8
#define BB 2
#define BETA 0.9f

#define THREADS 128
#define NBLK (BB*HH)        // 192

// ws float layout (no counter needed — two-kernel structure):
//  [CNT_BASE .. )  : count partials, ws[CNT_BASE + (t*16+d)*NBLK + blk]
//  [SM_BASE  .. )  : smooth partials, ws[SM_BASE + blk]
#define CNT_BASE 0
#define CNT_FLOATS (TT*HID*NBLK)     // 24576
#define SM_BASE (CNT_BASE + CNT_FLOATS)
#define DENOM 2359296.0f             // T*B*N*HID

// z (no bias) for one pixel's 3 input channels, 4 hid channels of this cg
__device__ __forceinline__ float4 proj4(float xa, float xb, float xc,
                                        const float* __restrict__ w0,
                                        const float* __restrict__ w1,
                                        const float* __restrict__ w2)
{
  float4 r;
  r.x = fmaf(xc, w2[0], fmaf(xb, w1[0], xa*w0[0]));
  r.y = fmaf(xc, w2[1], fmaf(xb, w1[1], xa*w0[1]));
  r.z = fmaf(xc, w2[2], fmaf(xb, w1[2], xa*w0[2]));
  r.w = fmaf(xc, w2[3], fmaf(xb, w1[3], xa*w0[3]));
  return r;
}

__global__ __launch_bounds__(THREADS)
void snn_main(const float* __restrict__ x,
              const float* __restrict__ wproj,
              const float* __restrict__ bproj,
              float* __restrict__ ws)
{
  __shared__ float4 xraw4[TT*3*72];    // 27648 B: raw x slab, [t][g] rows of 72 float4
  __shared__ float4 cbuf[2][WW*4];     // 12288 B: double-buffered vertical 3-sums [col][cg]
  __shared__ float4 cntslot[TT][2][4]; // per-t per-wave spike counts (lanes 0..3 = cg)
  __shared__ float  smslot[2];

  const int row  = blockIdx.x;    // 0..95
  const int b    = blockIdx.y;    // 0..1
  const int blk  = b*HH + row;
  const int tid  = threadIdx.x;
  const int lane = tid & 63;
  const int wv   = tid >> 6;
  const int cg   = tid & 3;       // channel group (4 hid channels)
  const int pbase= tid >> 2;      // 0..31

  // per-thread projection weights for this channel group
  float w0[4], w1[4], w2[4], bp[4];
#pragma unroll
  for (int j = 0; j < 4; ++j) {
    w0[j] = wproj[0*HID + cg*4 + j];
    w1[j] = wproj[1*HID + cg*4 + j];
    w2[j] = wproj[2*HID + cg*4 + j];
    bp[j] = bproj[cg*4 + j];
  }

  // ---- prologue: coalesced float4 copy of the whole x slab into LDS ----
  // 24 row-slabs (8t x 3 rows) x 72 float4 each = 1728 float4
#pragma unroll
  for (int i = 0; i < 14; ++i) {
    int idx = tid + THREADS*i;          // 0..1791
    if (idx < 1728) {
      int s = idx / 72;                 // slab: t*3 + g
      int q = idx - s*72;
      int t = s / 3;
      int g = s - t*3;
      int rr = row + g - 1;
      rr = (rr < 0) ? rr + HH : (rr >= HH ? rr - HH : rr);
      const float4* src = (const float4*)(x + ((size_t)(t*BB + b)*NPX + (size_t)rr*WW)*3);
      xraw4[s*72 + q] = src[q];
    }
  }
  __syncthreads();
  const float* xr = (const float*)xraw4;

  float4 v[3];
#pragma unroll
  for (int k = 0; k < 3; ++k) v[k] = make_float4(0.f,0.f,0.f,0.f);
  float smooth_acc = 0.f;
  const float inv9 = 1.0f/9.0f;

  for (int t = 0; t < TT; ++t) {
    float4* cb = cbuf[t & 1];
    // ---- phase 1: vertical 3-sum of z on core row (z recomputed from LDS x) ----
    float4 zc[3];
#pragma unroll
    for (int k = 0; k < 3; ++k) {
      int col = pbase + 32*k;
      int o0 = (t*288 +       col)*3;   // row-1
      int o1 = (t*288 +  96 + col)*3;   // row
      int o2 = (t*288 + 192 + col)*3;   // row+1
      float4 zm = proj4(xr[o0], xr[o0+1], xr[o0+2], w0, w1, w2);
      float4 z0 = proj4(xr[o1], xr[o1+1], xr[o1+2], w0, w1, w2);
      float4 zq = proj4(xr[o2], xr[o2+1], xr[o2+2], w0, w1, w2);
      zc[k] = z0;                         // core z (bias cancels in agg - z)
      float4 c;
      c.x = zm.x + z0.x + zq.x;
      c.y = zm.y + z0.y + zq.y;
      c.z = zm.z + z0.z + zq.z;
      c.w = zm.w + z0.w + zq.w;
      cb[col*4 + cg] = c;
    }
    __syncthreads();   // the only barrier per step (cbuf double-buffered)

    // ---- phase 2: horizontal 3-sum -> agg; LIF; reductions ----
    float4 cnt = make_float4(0.f,0.f,0.f,0.f);
#pragma unroll
    for (int k = 0; k < 3; ++k) {
      int col = pbase + 32*k;
      int cl = (col == 0)    ? (WW-1) : (col-1);
      int cr = (col == WW-1) ? 0      : (col+1);
      float4 s0 = cb[cl*4 + cg];
      float4 s1 = cb[col*4 + cg];
      float4 s2 = cb[cr*4 + cg];
      float gx = (s0.x + s1.x + s2.x) * inv9;   // agg minus bias
      float gy = (s0.y + s1.y + s2.y) * inv9;
      float gz = (s0.z + s1.z + s2.z) * inv9;
      float gw = (s0.w + s1.w + s2.w) * inv9;
      smooth_acc += fabsf(gx - zc[k].x);
      smooth_acc += fabsf(gy - zc[k].y);
      smooth_acc += fabsf(gz - zc[k].z);
      smooth_acc += fabsf(gw - zc[k].w);
      float vx = fmaf(BETA, v[k].x, gx + bp[0]);
      float vy = fmaf(BETA, v[k].y, gy + bp[1]);
      float vz = fmaf(BETA, v[k].z, gz + bp[2]);
      float vw = fmaf(BETA, v[k].w, gw + bp[3]);
      float sx = (vx > 1.0f) ? 1.0f : 0.0f;
      float sy = (vy > 1.0f) ? 1.0f : 0.0f;
      float sz = (vz > 1.0f) ? 1.0f : 0.0f;
      float sw = (vw > 1.0f) ? 1.0f : 0.0f;
      cnt.x += sx; cnt.y += sy; cnt.z += sz; cnt.w += sw;
      v[k].x = vx - sx;
      v[k].y = vy - sy;
      v[k].z = vz - sz;
      v[k].w = vw - sw;
    }

    // reduce cnt over lanes sharing (lane&3); lanes 0..3 hold cg 0..3
#pragma unroll
    for (int off = 4; off < 64; off <<= 1) {
      cnt.x += __shfl_xor(cnt.x, off);
      cnt.y += __shfl_xor(cnt.y, off);
      cnt.z += __shfl_xor(cnt.z, off);
      cnt.w += __shfl_xor(cnt.w, off);
    }
    if (lane < 4) cntslot[t][wv][lane] = cnt;
    // no barrier here: cntslot is read only after the epilogue barrier
  }

  // ---- epilogue: combine waves, publish partials (transposed layout) ----
#pragma unroll
  for (int off = 1; off < 64; off <<= 1)
    smooth_acc += __shfl_xor(smooth_acc, off);
  if (lane == 0) smslot[wv] = smooth_acc;
  __syncthreads();

  if (tid < 32) {                 // one (t, cg) each
    int t = tid >> 2, c4 = tid & 3;
    float4 a  = cntslot[t][0][c4];
    float4 bq = cntslot[t][1][c4];
    float tot[4] = { a.x+bq.x, a.y+bq.y, a.z+bq.z, a.w+bq.w };
#pragma unroll
    for (int comp = 0; comp < 4; ++comp)
      ws[CNT_BASE + (t*HID + c4*4 + comp)*NBLK + blk] = tot[comp];
  }
  if (tid == 0) ws[SM_BASE + blk] = smslot[0] + smslot[1];
}

__global__ __launch_bounds__(THREADS)
void snn_final(const float* __restrict__ ws,
               const float* __restrict__ whead,
               const float* __restrict__ bhead,
               float* __restrict__ out)
{
  __shared__ float cnt_s[TT][BB][HID];
  __shared__ float log_s[TT*BB*OUTC];
  __shared__ float redslot[4];
  const int tid  = threadIdx.x;
  const int lane = tid & 63;
  const int wv   = tid >> 6;

  // counts: 128 slots (t*16+d), each summing 192 contiguous floats (96 per batch)
  {
    const float4* src = (const float4*)(ws + CNT_BASE + tid*NBLK);
    float s0 = 0.f, s1 = 0.f;
#pragma unroll 8
    for (int q = 0; q < 24; ++q) { float4 a = src[q];  s0 += a.x+a.y+a.z+a.w; }
#pragma unroll 8
    for (int q = 24; q < 48; ++q){ float4 a = src[q];  s1 += a.x+a.y+a.z+a.w; }
    int t = tid >> 4, d = tid & 15;
    cnt_s[t][0][d] = s0;
    cnt_s[t][1][d] = s1;
  }
  __syncthreads();

  // logits_seq
  for (int i = tid; i < TT*BB*OUTC; i += THREADS) {
    int t  = i / (BB*OUTC);
    int r  = i - t*(BB*OUTC);
    int bq = r / OUTC;
    int o  = r - bq*OUTC;
    float acc = bhead[o];
#pragma unroll
    for (int d = 0; d < HID; ++d)
      acc = fmaf(cnt_s[t][bq][d] * (1.0f/9216.0f), whead[d*OUTC + o], acc);
    log_s[i] = acc;
    out[20 + i] = acc;
  }
  __syncthreads();

  if (tid < BB*OUTC) {            // time-mean readout
    int bq = tid / OUTC, o = tid - bq*OUTC;
    float a = 0.f;
#pragma unroll
    for (int t = 0; t < TT; ++t) a += log_s[(t*BB + bq)*OUTC + o];
    out[tid] = a * (1.0f/TT);
  }

  // sr and smooth, wave-parallel
  {
    float s_sr = (&cnt_s[0][0][0])[tid] + (&cnt_s[0][0][0])[tid + 128];
    float s_sm = ws[SM_BASE + tid] + ((tid < NBLK-THREADS) ? ws[SM_BASE + THREADS + tid] : 0.f);
#pragma unroll
    for (int off = 1; off < 64; off <<= 1) {
      s_sr += __shfl_xor(s_sr, off);
      s_sm += __shfl_xor(s_sm, off);
    }
    if (lane == 0) { redslot[wv] = s_sr; redslot[2+wv] = s_sm; }
    __syncthreads();
    if (tid == 0) {
      out[180] = (redslot[0] + redslot[1]) / DENOM;
      out[181] = (redslot[2] + redslot[3]) / DENOM;
    }
  }
}

extern "C" void kernel_launch(void* const* d_in, const int* in_sizes, int n_in,
                              void* d_out, int out_size, void* d_ws, size_t ws_size,
                              hipStream_t stream)
{
  const float* x     = (const float*)d_in[0];
  const float* wproj = (const float*)d_in[1];
  const float* bproj = (const float*)d_in[2];
  const float* whead = (const float*)d_in[3];
  const float* bhead = (const float*)d_in[4];
  float* out = (float*)d_out;
  float* ws  = (float*)d_ws;

  dim3 grid(HH, BB);
  snn_main<<<grid, dim3(THREADS), 0, stream>>>(x, wproj, bproj, ws);
  snn_final<<<1, dim3(THREADS), 0, stream>>>(ws, whead, bhead, out);
}

// Round 5
// 17.137 us; speedup vs baseline: 2.3848x; 1.2563x over previous
//
#include <hip/hip_runtime.h>

#define HH 96
#define WW 96
#define NPX (HH*WW)         // 9216
#define HID 16
#define OUTC 10
#define TT 8
#define BB 2
#define BETA 0.9f

#define THREADS 384         // 6 waves; thread = (col 0..95) x (cg 0..3)
#define NBLK (BB*HH)        // 192

// ws float layout:
//  [0 .. CNT_FLOATS)  : count partials, ws[(t*16+d)*NBLK + blk]
//  [SM_BASE .. )      : smooth partials, ws[SM_BASE + blk]
#define CNT_FLOATS (TT*HID*NBLK)     // 24576
#define SM_BASE CNT_FLOATS
#define DENOM 2359296.0f             // T*B*N*HID

#define SLABW 292        // padded words per (t,g) x-slab (73 float4) — breaks mod-32 bank aliasing
#define VPAD 97          // vbuf row stride in float4

// z (no bias): project 3 input channels to this thread's 4 hid channels
__device__ __forceinline__ float4 proj4(float xa, float xb, float xc,
                                        const float* w0, const float* w1, const float* w2)
{
  float4 r;
  r.x = fmaf(xc, w2[0], fmaf(xb, w1[0], xa*w0[0]));
  r.y = fmaf(xc, w2[1], fmaf(xb, w1[1], xa*w0[1]));
  r.z = fmaf(xc, w2[2], fmaf(xb, w1[2], xa*w0[2]));
  r.w = fmaf(xc, w2[3], fmaf(xb, w1[3], xa*w0[3]));
  return r;
}

__global__ __launch_bounds__(THREADS)
void snn_main(const float* __restrict__ x,
              const float* __restrict__ wproj,
              const float* __restrict__ bproj,
              float* __restrict__ ws)
{
  __shared__ float4 xraw4[24*73];       // 28032 B: raw x, slab s = t*3+g, padded stride 73
  __shared__ float4 vbuf[TT*VPAD];      // 12416 B: vertical x 3-sums, [t*97 + col]
  __shared__ float4 cntslot[TT][6][4];  // 3072 B: per-t per-wave spike counts
  __shared__ float  smslot[6];

  const int row  = blockIdx.x;    // 0..95
  const int b    = blockIdx.y;    // 0..1
  const int blk  = b*HH + row;
  const int tid  = threadIdx.x;
  const int lane = tid & 63;
  const int wv   = tid >> 6;      // 0..5
  const int cg   = tid & 3;       // channel group (4 hid channels)
  const int col  = tid >> 2;      // 0..95

  // per-thread projection weights for this channel group
  float w0[4], w1[4], w2[4], bp[4];
#pragma unroll
  for (int j = 0; j < 4; ++j) {
    w0[j] = wproj[0*HID + cg*4 + j];
    w1[j] = wproj[1*HID + cg*4 + j];
    w2[j] = wproj[2*HID + cg*4 + j];
    bp[j] = bproj[cg*4 + j];
  }

  // ---- prologue: coalesced float4 copy of the whole x slab into LDS ----
  // 24 slabs (8t x 3 rows) x 72 float4 = 1728 float4, padded dest stride 73
#pragma unroll
  for (int i = 0; i < 5; ++i) {
    int idx = tid + THREADS*i;          // 0..1919
    if (idx < 1728) {
      int s = idx / 72;                 // slab = t*3 + g
      int q = idx - s*72;
      int t = s / 3;
      int g = s - t*3;
      int rr = row + g - 1;
      rr = (rr < 0) ? rr + HH : (rr >= HH ? rr - HH : rr);
      const float4* src = (const float4*)(x + ((size_t)(t*BB + b)*NPX + (size_t)rr*WW)*3);
      xraw4[s*73 + q] = src[q];
    }
  }
  __syncthreads();
  const float* xr = (const float*)xraw4;

  // ---- phase A: vertical x 3-sums for ALL 8 t (each thread does 2 t's) ----
#pragma unroll
  for (int i = 0; i < 2; ++i) {
    int t = cg*2 + i;                   // cg 0..3 x i 0..1 covers t 0..7
    int base = t*3*SLABW + col*3;       // word offset of (t, g=0, col, ch0)
    float s0 = xr[base            ] + xr[base +   SLABW    ] + xr[base + 2*SLABW    ];
    float s1 = xr[base + 1        ] + xr[base +   SLABW + 1] + xr[base + 2*SLABW + 1];
    float s2 = xr[base + 2        ] + xr[base +   SLABW + 2] + xr[base + 2*SLABW + 2];
    vbuf[t*VPAD + col] = make_float4(s0, s1, s2, 0.f);
  }
  __syncthreads();      // last barrier before the epilogue — phase B is barrier-free

  // ---- phase B: horizontal 3-sum -> box9(x); project; LIF scan (registers) ----
  const int cl = (col == 0)    ? (WW-1) : (col-1);
  const int cr = (col == WW-1) ? 0      : (col+1);
  float4 v = make_float4(0.f, 0.f, 0.f, 0.f);
  float sm = 0.f;
  float cnt[TT][4];
#pragma unroll
  for (int t = 0; t < TT; ++t) { cnt[t][0]=0.f; cnt[t][1]=0.f; cnt[t][2]=0.f; cnt[t][3]=0.f; }
  const float inv9 = 1.0f/9.0f;

#pragma unroll
  for (int t = 0; t < TT; ++t) {
    float4 a0 = vbuf[t*VPAD + cl];
    float4 a1 = vbuf[t*VPAD + col];
    float4 a2 = vbuf[t*VPAD + cr];
    float bx = a0.x + a1.x + a2.x;      // box9 sum of x, 3 channels
    float by = a0.y + a1.y + a2.y;
    float bz = a0.z + a1.z + a2.z;
    int cb = (t*3 + 1)*SLABW + col*3;   // core pixel x
    float xc0 = xr[cb], xc1 = xr[cb+1], xc2 = xr[cb+2];
    float4 pb = proj4(bx, by, bz, w0, w1, w2);     // proj(box9 x)   (no bias)
    float4 pz = proj4(xc0, xc1, xc2, w0, w1, w2);  // proj(core x)   (no bias)
    float ax = pb.x*inv9, ay = pb.y*inv9, az = pb.z*inv9, aw = pb.w*inv9;
    sm += fabsf(ax - pz.x) + fabsf(ay - pz.y) + fabsf(az - pz.z) + fabsf(aw - pz.w);
    float vx = fmaf(BETA, v.x, ax + bp[0]);
    float vy = fmaf(BETA, v.y, ay + bp[1]);
    float vz = fmaf(BETA, v.z, az + bp[2]);
    float vw = fmaf(BETA, v.w, aw + bp[3]);
    float sx = (vx > 1.0f) ? 1.0f : 0.0f;
    float sy = (vy > 1.0f) ? 1.0f : 0.0f;
    float sz = (vz > 1.0f) ? 1.0f : 0.0f;
    float sw = (vw > 1.0f) ? 1.0f : 0.0f;
    cnt[t][0] += sx; cnt[t][1] += sy; cnt[t][2] += sz; cnt[t][3] += sw;
    v.x = vx - sx; v.y = vy - sy; v.z = vz - sz; v.w = vw - sw;
  }

  // ---- epilogue: reduce counts over the wave's 16 cols (lanes sharing lane&3) ----
#pragma unroll
  for (int t = 0; t < TT; ++t) {
#pragma unroll
    for (int off = 4; off < 64; off <<= 1) {
      cnt[t][0] += __shfl_xor(cnt[t][0], off);
      cnt[t][1] += __shfl_xor(cnt[t][1], off);
      cnt[t][2] += __shfl_xor(cnt[t][2], off);
      cnt[t][3] += __shfl_xor(cnt[t][3], off);
    }
  }
  if (lane < 4) {      // lane == cg for lanes 0..3
#pragma unroll
    for (int t = 0; t < TT; ++t)
      cntslot[t][wv][lane] = make_float4(cnt[t][0], cnt[t][1], cnt[t][2], cnt[t][3]);
  }

  // smooth: full wave butterfly
#pragma unroll
  for (int off = 1; off < 64; off <<= 1)
    sm += __shfl_xor(sm, off);
  if (lane == 0) smslot[wv] = sm;
  __syncthreads();

  if (tid < 32) {                 // one (t, cg) each; combine 6 waves
    int t = tid >> 2, c4 = tid & 3;
    float4 s = cntslot[t][0][c4];
#pragma unroll
    for (int w = 1; w < 6; ++w) {
      float4 a = cntslot[t][w][c4];
      s.x += a.x; s.y += a.y; s.z += a.z; s.w += a.w;
    }
    float tot[4] = { s.x, s.y, s.z, s.w };
#pragma unroll
    for (int comp = 0; comp < 4; ++comp)
      ws[(t*HID + c4*4 + comp)*NBLK + blk] = tot[comp];
  }
  if (tid == 0)
    ws[SM_BASE + blk] = smslot[0]+smslot[1]+smslot[2]+smslot[3]+smslot[4]+smslot[5];
}

__global__ __launch_bounds__(256)
void snn_final(const float* __restrict__ ws,
               const float* __restrict__ whead,
               const float* __restrict__ bhead,
               float* __restrict__ out)
{
  __shared__ float cnt_s[TT][BB][HID];   // 256 floats
  __shared__ float log_s[TT*BB*OUTC];    // 160 floats
  __shared__ float redslot[8];
  const int tid  = threadIdx.x;
  const int lane = tid & 63;
  const int wv   = tid >> 6;

  // counts: 128 slots (t*16+d) x 2 halves (= batch), each sums 24 contiguous float4
  {
    int slot = tid >> 1, half = tid & 1;   // half == batch (blk = b*96 + row)
    const float4* src = (const float4*)(ws + (size_t)slot*NBLK) + half*24;
    float s = 0.f;
#pragma unroll
    for (int q = 0; q < 24; ++q) { float4 a = src[q]; s += a.x+a.y+a.z+a.w; }
    int t = slot >> 4, d = slot & 15;
    cnt_s[t][half][d] = s;
  }
  __syncthreads();

  // logits_seq: 160 outputs
  if (tid < TT*BB*OUTC) {
    int t  = tid / (BB*OUTC);
    int r  = tid - t*(BB*OUTC);
    int bq = r / OUTC;
    int o  = r - bq*OUTC;
    float acc = bhead[o];
#pragma unroll
    for (int d = 0; d < HID; ++d)
      acc = fmaf(cnt_s[t][bq][d] * (1.0f/9216.0f), whead[d*OUTC + o], acc);
    log_s[tid] = acc;
    out[20 + tid] = acc;
  }
  __syncthreads();

  if (tid < BB*OUTC) {            // time-mean readout
    int bq = tid / OUTC, o = tid - bq*OUTC;
    float a = 0.f;
#pragma unroll
    for (int t = 0; t < TT; ++t) a += log_s[(t*BB + bq)*OUTC + o];
    out[tid] = a * (1.0f/TT);
  }

  // sr (256 floats, one per thread) and smooth (192 floats), wave-parallel
  {
    float s_sr = (&cnt_s[0][0][0])[tid];
    float s_sm = (tid < NBLK) ? ws[SM_BASE + tid] : 0.f;
#pragma unroll
    for (int off = 1; off < 64; off <<= 1) {
      s_sr += __shfl_xor(s_sr, off);
      s_sm += __shfl_xor(s_sm, off);
    }
    if (lane == 0) { redslot[wv] = s_sr; redslot[4+wv] = s_sm; }
    __syncthreads();
    if (tid == 0) {
      out[180] = (redslot[0]+redslot[1]+redslot[2]+redslot[3]) / DENOM;
      out[181] = (redslot[4]+redslot[5]+redslot[6]+redslot[7]) / DENOM;
    }
  }
}

extern "C" void kernel_launch(void* const* d_in, const int* in_sizes, int n_in,
                              void* d_out, int out_size, void* d_ws, size_t ws_size,
                              hipStream_t stream)
{
  const float* x     = (const float*)d_in[0];
  const float* wproj = (const float*)d_in[1];
  const float* bproj = (const float*)d_in[2];
  const float* whead = (const float*)d_in[3];
  const float* bhead = (const float*)d_in[4];
  float* out = (float*)d_out;
  float* ws  = (float*)d_ws;

  dim3 grid(HH, BB);
  snn_main<<<grid, dim3(THREADS), 0, stream>>>(x, wproj, bproj, ws);
  snn_final<<<1, dim3(256), 0, stream>>>(ws, whead, bhead, out);
}

// Round 6
// 13.312 us; speedup vs baseline: 3.0700x; 1.2873x over previous
//
#include <hip/hip_runtime.h>

#define HH 96
#define WW 96
#define NPX (HH*WW)         // 9216
#define HID 16
#define OUTC 10
#define TT 8
#define BB 2
#define BETA 0.9f

#define THREADS 384         // 6 waves; thread = (col 0..95) x (cg 0..3)
#define NBLK (BB*HH)        // 192

// ws layout:
//  u32   [0 .. 6144)        : packed count partials, wsu[(t*4+cg)*NBLK + blk],
//                             byte j = count for channel d = cg*4+j  (<=96)
//  float [6144 .. 6336)     : smooth partials, ws[SM_BASE + blk]
#define SM_BASE (TT*4*NBLK)          // 6144
#define DENOM 2359296.0f             // T*B*N*HID

#define SLABW 292        // padded words per (t,g) x-slab (73 float4)
#define VPAD 97          // vbuf row stride in float4

// z (no bias): project 3 input channels to this thread's 4 hid channels
__device__ __forceinline__ float4 proj4(float xa, float xb, float xc,
                                        const float* w0, const float* w1, const float* w2)
{
  float4 r;
  r.x = fmaf(xc, w2[0], fmaf(xb, w1[0], xa*w0[0]));
  r.y = fmaf(xc, w2[1], fmaf(xb, w1[1], xa*w0[1]));
  r.z = fmaf(xc, w2[2], fmaf(xb, w1[2], xa*w0[2]));
  r.w = fmaf(xc, w2[3], fmaf(xb, w1[3], xa*w0[3]));
  return r;
}

__global__ __launch_bounds__(THREADS)
void snn_main(const float* __restrict__ x,
              const float* __restrict__ wproj,
              const float* __restrict__ bproj,
              float* __restrict__ ws)
{
  __shared__ float4 xraw4[24*73];        // 28032 B: raw x, slab s = t*3+g, stride 73
  __shared__ float4 vbuf[TT*VPAD];       // 12416 B: vertical x 3-sums, [t*97 + col]
  __shared__ unsigned cslot[TT][6][4];   // 768 B: per-t per-wave packed counts
  __shared__ float  smslot[6];

  const int row  = blockIdx.x;    // 0..95
  const int b    = blockIdx.y;    // 0..1
  const int blk  = b*HH + row;
  const int tid  = threadIdx.x;
  const int lane = tid & 63;
  const int wv   = tid >> 6;      // 0..5
  const int cg   = tid & 3;       // channel group (4 hid channels)
  const int col  = tid >> 2;      // 0..95

  // per-thread projection weights for this channel group
  float w0[4], w1[4], w2[4], bp[4];
#pragma unroll
  for (int j = 0; j < 4; ++j) {
    w0[j] = wproj[0*HID + cg*4 + j];
    w1[j] = wproj[1*HID + cg*4 + j];
    w2[j] = wproj[2*HID + cg*4 + j];
    bp[j] = bproj[cg*4 + j];
  }

  // ---- prologue: coalesced float4 copy of the whole x slab into LDS ----
#pragma unroll
  for (int i = 0; i < 5; ++i) {
    int idx = tid + THREADS*i;          // 0..1919
    if (idx < 1728) {
      int s = idx / 72;                 // slab = t*3 + g
      int q = idx - s*72;
      int t = s / 3;
      int g = s - t*3;
      int rr = row + g - 1;
      rr = (rr < 0) ? rr + HH : (rr >= HH ? rr - HH : rr);
      const float4* src = (const float4*)(x + ((size_t)(t*BB + b)*NPX + (size_t)rr*WW)*3);
      xraw4[s*73 + q] = src[q];
    }
  }
  __syncthreads();
  const float* xr = (const float*)xraw4;

  // ---- phase A: vertical x 3-sums for ALL 8 t (each thread does 2 t's) ----
#pragma unroll
  for (int i = 0; i < 2; ++i) {
    int t = cg*2 + i;
    int base = t*3*SLABW + col*3;
    float s0 = xr[base    ] + xr[base + SLABW    ] + xr[base + 2*SLABW    ];
    float s1 = xr[base + 1] + xr[base + SLABW + 1] + xr[base + 2*SLABW + 1];
    float s2 = xr[base + 2] + xr[base + SLABW + 2] + xr[base + 2*SLABW + 2];
    vbuf[t*VPAD + col] = make_float4(s0, s1, s2, 0.f);
  }
  __syncthreads();

  // ---- phase B: box9 -> project -> LIF scan; ballot spike counting ----
  const int cl = (col == 0)    ? (WW-1) : (col-1);
  const int cr = (col == WW-1) ? 0      : (col+1);
  float4 v = make_float4(0.f, 0.f, 0.f, 0.f);
  float sm = 0.f;
  unsigned packw[TT];
  const float inv9 = 1.0f/9.0f;
  const unsigned long long fm = 0x1111111111111111ULL << cg;  // lanes with lane%4==cg

#pragma unroll
  for (int t = 0; t < TT; ++t) {
    float4 a0 = vbuf[t*VPAD + cl];
    float4 a1 = vbuf[t*VPAD + col];
    float4 a2 = vbuf[t*VPAD + cr];
    float bx = a0.x + a1.x + a2.x;
    float by = a0.y + a1.y + a2.y;
    float bz = a0.z + a1.z + a2.z;
    int cb = (t*3 + 1)*SLABW + col*3;
    float xc0 = xr[cb], xc1 = xr[cb+1], xc2 = xr[cb+2];
    float4 pb = proj4(bx, by, bz, w0, w1, w2);
    float4 pz = proj4(xc0, xc1, xc2, w0, w1, w2);
    float ax = pb.x*inv9, ay = pb.y*inv9, az = pb.z*inv9, aw = pb.w*inv9;
    sm += fabsf(ax - pz.x) + fabsf(ay - pz.y) + fabsf(az - pz.z) + fabsf(aw - pz.w);
    float vx = fmaf(BETA, v.x, ax + bp[0]);
    float vy = fmaf(BETA, v.y, ay + bp[1]);
    float vz = fmaf(BETA, v.z, az + bp[2]);
    float vw = fmaf(BETA, v.w, aw + bp[3]);
    bool b0 = vx > 1.0f, b1 = vy > 1.0f, b2 = vz > 1.0f, b3 = vw > 1.0f;
    // per-wave spike counts via ballot (one bit per pixel-channel)
    unsigned long long m0 = __ballot(b0);
    unsigned long long m1 = __ballot(b1);
    unsigned long long m2 = __ballot(b2);
    unsigned long long m3 = __ballot(b3);
    unsigned c0 = (unsigned)__popcll(m0 & fm);
    unsigned c1 = (unsigned)__popcll(m1 & fm);
    unsigned c2 = (unsigned)__popcll(m2 & fm);
    unsigned c3 = (unsigned)__popcll(m3 & fm);
    packw[t] = c0 | (c1 << 8) | (c2 << 16) | (c3 << 24);
    v.x = vx - (b0 ? 1.0f : 0.0f);
    v.y = vy - (b1 ? 1.0f : 0.0f);
    v.z = vz - (b2 ? 1.0f : 0.0f);
    v.w = vw - (b3 ? 1.0f : 0.0f);
  }

  // ---- epilogue ----
  if (lane < 4) {                 // lane == cg for lanes 0..3
#pragma unroll
    for (int t = 0; t < TT; ++t)
      cslot[t][wv][lane] = packw[t];
  }
#pragma unroll
  for (int off = 1; off < 64; off <<= 1)
    sm += __shfl_xor(sm, off);
  if (lane == 0) smslot[wv] = sm;
  __syncthreads();

  unsigned* wsu = (unsigned*)ws;
  if (tid < 32) {                 // one (t, cg) each; combine 6 waves (bytewise-safe)
    int t = tid >> 2, c4 = tid & 3;
    unsigned s = cslot[t][0][c4] + cslot[t][1][c4] + cslot[t][2][c4]
               + cslot[t][3][c4] + cslot[t][4][c4] + cslot[t][5][c4];
    wsu[(t*4 + c4)*NBLK + blk] = s;
  }
  if (tid == 0)
    ws[SM_BASE + blk] = smslot[0]+smslot[1]+smslot[2]+smslot[3]+smslot[4]+smslot[5];
}

__global__ __launch_bounds__(256)
void snn_final(const float* __restrict__ ws,
               const float* __restrict__ whead,
               const float* __restrict__ bhead,
               float* __restrict__ out)
{
  __shared__ uint4 part_s[32][8];        // 4 KB: per-slot per-sub channel counts
  __shared__ float cnt_s[TT][BB][HID];   // 256 floats
  __shared__ float log_s[TT*BB*OUTC];    // 160 floats
  __shared__ float redslot[8];
  const int tid  = threadIdx.x;
  const int lane = tid & 63;
  const int wv   = tid >> 6;

  // stage 1: 32 slots (t*4+cg) x 8 subs; each thread sums 24 packed u32 (6 uint4)
  {
    const unsigned* wsu = (const unsigned*)ws;
    int slot = tid >> 3, sub = tid & 7;
    const uint4* src = (const uint4*)(wsu + slot*NBLK) + sub*6;
    unsigned c0 = 0, c1 = 0, c2 = 0, c3 = 0;
#pragma unroll
    for (int q = 0; q < 6; ++q) {
      uint4 a = src[q];
      unsigned p0 = a.x + a.y, p1 = a.z + a.w;   // bytes <=96, pair-sum <=192: safe
      c0 += (p0 & 0xffu)        + (p1 & 0xffu);
      c1 += ((p0 >> 8) & 0xffu) + ((p1 >> 8) & 0xffu);
      c2 += ((p0 >> 16) & 0xffu)+ ((p1 >> 16) & 0xffu);
      c3 += (p0 >> 24)          + (p1 >> 24);
    }
    part_s[slot][sub] = make_uint4(c0, c1, c2, c3);
  }
  __syncthreads();

  // stage 2: 64 threads: (slot, half=batch): combine 4 subs -> cnt_s floats
  if (tid < 64) {
    int slot = tid >> 1, half = tid & 1;
    uint4 a = part_s[slot][half*4 + 0];
    uint4 b = part_s[slot][half*4 + 1];
    uint4 c = part_s[slot][half*4 + 2];
    uint4 d = part_s[slot][half*4 + 3];
    int t = slot >> 2, cg = slot & 3;
    cnt_s[t][half][cg*4 + 0] = (float)(a.x + b.x + c.x + d.x);
    cnt_s[t][half][cg*4 + 1] = (float)(a.y + b.y + c.y + d.y);
    cnt_s[t][half][cg*4 + 2] = (float)(a.z + b.z + c.z + d.z);
    cnt_s[t][half][cg*4 + 3] = (float)(a.w + b.w + c.w + d.w);
  }
  __syncthreads();

  // logits_seq: 160 outputs
  if (tid < TT*BB*OUTC) {
    int t  = tid / (BB*OUTC);
    int r  = tid - t*(BB*OUTC);
    int bq = r / OUTC;
    int o  = r - bq*OUTC;
    float acc = bhead[o];
#pragma unroll
    for (int d = 0; d < HID; ++d)
      acc = fmaf(cnt_s[t][bq][d] * (1.0f/9216.0f), whead[d*OUTC + o], acc);
    log_s[tid] = acc;
    out[20 + tid] = acc;
  }
  __syncthreads();

  if (tid < BB*OUTC) {            // time-mean readout
    int bq = tid / OUTC, o = tid - bq*OUTC;
    float a = 0.f;
#pragma unroll
    for (int t = 0; t < TT; ++t) a += log_s[(t*BB + bq)*OUTC + o];
    out[tid] = a * (1.0f/TT);
  }

  // sr (256 floats, one per thread) and smooth (192 floats), wave-parallel
  {
    float s_sr = (&cnt_s[0][0][0])[tid];
    float s_sm = (tid < NBLK) ? ws[SM_BASE + tid] : 0.f;
#pragma unroll
    for (int off = 1; off < 64; off <<= 1) {
      s_sr += __shfl_xor(s_sr, off);
      s_sm += __shfl_xor(s_sm, off);
    }
    if (lane == 0) { redslot[wv] = s_sr; redslot[4+wv] = s_sm; }
    __syncthreads();
    if (tid == 0) {
      out[180] = (redslot[0]+redslot[1]+redslot[2]+redslot[3]) / DENOM;
      out[181] = (redslot[4]+redslot[5]+redslot[6]+redslot[7]) / DENOM;
    }
  }
}

extern "C" void kernel_launch(void* const* d_in, const int* in_sizes, int n_in,
                              void* d_out, int out_size, void* d_ws, size_t ws_size,
                              hipStream_t stream)
{
  const float* x     = (const float*)d_in[0];
  const float* wproj = (const float*)d_in[1];
  const float* bproj = (const float*)d_in[2];
  const float* whead = (const float*)d_in[3];
  const float* bhead = (const float*)d_in[4];
  float* out = (float*)d_out;
  float* ws  = (float*)d_ws;

  dim3 grid(HH, BB);
  snn_main<<<grid, dim3(THREADS), 0, stream>>>(x, wproj, bproj, ws);
  snn_final<<<1, dim3(256), 0, stream>>>(ws, whead, bhead, out);
}

// Round 7
// 12.997 us; speedup vs baseline: 3.1445x; 1.0243x over previous
//
#include <hip/hip_runtime.h>

#define HH 96
#define WW 96
#define NPX (HH*WW)         // 9216
#define HID 16
#define OUTC 10
#define TT 8
#define BB 2
#define BETA 0.9f

#define THREADS 384         // 6 waves; thread = (col 0..95) x (cg 0..3)
#define NBLK (BB*HH)        // 192

// ws layout:
//  u32   [0 .. 6144)        : packed count partials, wsu[(t*4+cg)*NBLK + blk],
//                             byte j = count for channel d = cg*4+j  (<=96)
//  float [6144 .. 6336)     : smooth partials, ws[SM_BASE + blk]
#define SM_BASE (TT*4*NBLK)          // 6144
#define DENOM 2359296.0f             // T*B*N*HID

#define SLABW 292        // padded words per (t,g) x-slab (73 float4) — breaks cross-slab bank aliasing
#define VPAD 97          // vbuf row stride in float4

// z (no bias): project 3 input channels to this thread's 4 hid channels
__device__ __forceinline__ float4 proj4(float xa, float xb, float xc,
                                        const float* w0, const float* w1, const float* w2)
{
  float4 r;
  r.x = fmaf(xc, w2[0], fmaf(xb, w1[0], xa*w0[0]));
  r.y = fmaf(xc, w2[1], fmaf(xb, w1[1], xa*w0[1]));
  r.z = fmaf(xc, w2[2], fmaf(xb, w1[2], xa*w0[2]));
  r.w = fmaf(xc, w2[3], fmaf(xb, w1[3], xa*w0[3]));
  return r;
}

__global__ __launch_bounds__(THREADS)
void snn_main(const float* __restrict__ x,
              const float* __restrict__ wproj,
              const float* __restrict__ bproj,
              float* __restrict__ ws)
{
  __shared__ float4 xraw4[24*73];        // 28032 B: raw x, slab s = t*3+g, stride 73
  __shared__ float4 vbuf[TT*VPAD];       // 12416 B: vertical x 3-sums, [t*97 + col]
  __shared__ unsigned cslot[TT][6][4];   // 768 B: per-t per-wave packed counts
  __shared__ float  smslot[6];

  const int row  = blockIdx.x;    // 0..95
  const int b    = blockIdx.y;    // 0..1
  const int blk  = b*HH + row;
  const int tid  = threadIdx.x;
  const int lane = tid & 63;
  const int wv   = tid >> 6;      // 0..5
  const int cg   = tid & 3;       // channel group (4 hid channels)
  const int col  = tid >> 2;      // 0..95

  // per-thread projection weights for this channel group
  float w0[4], w1[4], w2[4], bp[4];
#pragma unroll
  for (int j = 0; j < 4; ++j) {
    w0[j] = wproj[0*HID + cg*4 + j];
    w1[j] = wproj[1*HID + cg*4 + j];
    w2[j] = wproj[2*HID + cg*4 + j];
    bp[j] = bproj[cg*4 + j];
  }

  // ---- prologue: coalesced float4 copy of the whole x slab into LDS ----
#pragma unroll
  for (int i = 0; i < 5; ++i) {
    int idx = tid + THREADS*i;          // 0..1919
    if (idx < 1728) {
      int s = idx / 72;                 // slab = t*3 + g
      int q = idx - s*72;
      int t = s / 3;
      int g = s - t*3;
      int rr = row + g - 1;
      rr = (rr < 0) ? rr + HH : (rr >= HH ? rr - HH : rr);
      const float4* src = (const float4*)(x + ((size_t)(t*BB + b)*NPX + (size_t)rr*WW)*3);
      xraw4[s*73 + q] = src[q];
    }
  }
  __syncthreads();
  const float* xr = (const float*)xraw4;

  // ---- phase A: vertical x 3-sums for ALL 8 t (each thread does 2 t's) ----
#pragma unroll
  for (int i = 0; i < 2; ++i) {
    int t = cg*2 + i;
    int base = t*3*SLABW + col*3;
    float s0 = xr[base    ] + xr[base + SLABW    ] + xr[base + 2*SLABW    ];
    float s1 = xr[base + 1] + xr[base + SLABW + 1] + xr[base + 2*SLABW + 1];
    float s2 = xr[base + 2] + xr[base + SLABW + 2] + xr[base + 2*SLABW + 2];
    vbuf[t*VPAD + col] = make_float4(s0, s1, s2, 0.f);
  }
  __syncthreads();

  // ---- phase B: box9 -> project -> LIF scan; ballot spike counting ----
  const int cl = (col == 0)    ? (WW-1) : (col-1);
  const int cr = (col == WW-1) ? 0      : (col+1);
  float4 v = make_float4(0.f, 0.f, 0.f, 0.f);
  float sm = 0.f;
  unsigned packw[TT];
  const float inv9 = 1.0f/9.0f;
  const unsigned long long fm = 0x1111111111111111ULL << cg;  // lanes with lane%4==cg

#pragma unroll
  for (int t = 0; t < TT; ++t) {
    float4 a0 = vbuf[t*VPAD + cl];
    float4 a1 = vbuf[t*VPAD + col];
    float4 a2 = vbuf[t*VPAD + cr];
    float bx = a0.x + a1.x + a2.x;
    float by = a0.y + a1.y + a2.y;
    float bz = a0.z + a1.z + a2.z;
    int cb = (t*3 + 1)*SLABW + col*3;
    float xc0 = xr[cb], xc1 = xr[cb+1], xc2 = xr[cb+2];
    float4 pb = proj4(bx, by, bz, w0, w1, w2);
    float4 pz = proj4(xc0, xc1, xc2, w0, w1, w2);
    float ax = pb.x*inv9, ay = pb.y*inv9, az = pb.z*inv9, aw = pb.w*inv9;
    sm += fabsf(ax - pz.x) + fabsf(ay - pz.y) + fabsf(az - pz.z) + fabsf(aw - pz.w);
    float vx = fmaf(BETA, v.x, ax + bp[0]);
    float vy = fmaf(BETA, v.y, ay + bp[1]);
    float vz = fmaf(BETA, v.z, az + bp[2]);
    float vw = fmaf(BETA, v.w, aw + bp[3]);
    bool b0 = vx > 1.0f, b1 = vy > 1.0f, b2 = vz > 1.0f, b3 = vw > 1.0f;
    unsigned long long m0 = __ballot(b0);
    unsigned long long m1 = __ballot(b1);
    unsigned long long m2 = __ballot(b2);
    unsigned long long m3 = __ballot(b3);
    unsigned c0 = (unsigned)__popcll(m0 & fm);
    unsigned c1 = (unsigned)__popcll(m1 & fm);
    unsigned c2 = (unsigned)__popcll(m2 & fm);
    unsigned c3 = (unsigned)__popcll(m3 & fm);
    packw[t] = c0 | (c1 << 8) | (c2 << 16) | (c3 << 24);
    v.x = vx - (b0 ? 1.0f : 0.0f);
    v.y = vy - (b1 ? 1.0f : 0.0f);
    v.z = vz - (b2 ? 1.0f : 0.0f);
    v.w = vw - (b3 ? 1.0f : 0.0f);
  }

  // ---- epilogue ----
  if (lane < 4) {                 // lane == cg for lanes 0..3
#pragma unroll
    for (int t = 0; t < TT; ++t)
      cslot[t][wv][lane] = packw[t];
  }
#pragma unroll
  for (int off = 1; off < 64; off <<= 1)
    sm += __shfl_xor(sm, off);
  if (lane == 0) smslot[wv] = sm;
  __syncthreads();

  unsigned* wsu = (unsigned*)ws;
  if (tid < 32) {                 // one (t, cg) each; combine 6 waves (bytewise-safe)
    int t = tid >> 2, c4 = tid & 3;
    unsigned s = cslot[t][0][c4] + cslot[t][1][c4] + cslot[t][2][c4]
               + cslot[t][3][c4] + cslot[t][4][c4] + cslot[t][5][c4];
    wsu[(t*4 + c4)*NBLK + blk] = s;
  }
  if (tid == 0)
    ws[SM_BASE + blk] = smslot[0]+smslot[1]+smslot[2]+smslot[3]+smslot[4]+smslot[5];
}

__global__ __launch_bounds__(320)
void snn_final(const float* __restrict__ ws,
               const float* __restrict__ whead,
               const float* __restrict__ bhead,
               float* __restrict__ out)
{
  __shared__ float cnt_s[TT][BB][HID];   // 256 floats
  const int tid  = threadIdx.x;

  // smooth wave (threads 256..319): issue global loads immediately (overlaps stage 1)
  float smacc = 0.f;
  if (tid >= 256) {
    int i = tid - 256;
    smacc = ws[SM_BASE + i] + ws[SM_BASE + 64 + i] + ws[SM_BASE + 128 + i];
  }

  // stage 1 (threads 0..255 = waves 0..3, full waves): 32 slots (t*4+cg) x 8 subs;
  // each thread sums 24 packed u32 (6 uint4), then quad-reduce over subs via shfl.
  if (tid < 256) {
    const unsigned* wsu = (const unsigned*)ws;
    int slot = tid >> 3, sub = tid & 7;
    const uint4* src = (const uint4*)(wsu + slot*NBLK) + sub*6;
    unsigned c0 = 0, c1 = 0, c2 = 0, c3 = 0;
#pragma unroll
    for (int q = 0; q < 6; ++q) {
      uint4 a = src[q];
      unsigned p0 = a.x + a.y, p1 = a.z + a.w;   // bytes <=96, pair-sum <=192: safe
      c0 += (p0 & 0xffu)        + (p1 & 0xffu);
      c1 += ((p0 >> 8) & 0xffu) + ((p1 >> 8) & 0xffu);
      c2 += ((p0 >> 16) & 0xffu)+ ((p1 >> 16) & 0xffu);
      c3 += (p0 >> 24)          + (p1 >> 24);
    }
    // reduce over sub within {0..3} (batch 0) and {4..7} (batch 1)
    c0 += __shfl_xor(c0, 1); c1 += __shfl_xor(c1, 1);
    c2 += __shfl_xor(c2, 1); c3 += __shfl_xor(c3, 1);
    c0 += __shfl_xor(c0, 2); c1 += __shfl_xor(c1, 2);
    c2 += __shfl_xor(c2, 2); c3 += __shfl_xor(c3, 2);
    if ((sub & 3) == 0) {
      int half = sub >> 2;                // 0 -> batch 0, 1 -> batch 1
      int t = slot >> 2, cg = slot & 3;
      cnt_s[t][half][cg*4 + 0] = (float)c0;
      cnt_s[t][half][cg*4 + 1] = (float)c1;
      cnt_s[t][half][cg*4 + 2] = (float)c2;
      cnt_s[t][half][cg*4 + 3] = (float)c3;
    }
  }
  __syncthreads();    // the only barrier

  if (tid < 160) {
    // logits_seq: out[20 + (t,b,o)]
    int t  = tid / (BB*OUTC);
    int r  = tid - t*(BB*OUTC);
    int bq = r / OUTC;
    int o  = r - bq*OUTC;
    float acc = bhead[o];
#pragma unroll
    for (int d = 0; d < HID; ++d)
      acc = fmaf(cnt_s[t][bq][d] * (1.0f/9216.0f), whead[d*OUTC + o], acc);
    out[20 + tid] = acc;
  } else if (tid < 180) {
    // time-mean readout, independent of logits threads
    int r  = tid - 160;
    int bq = r / OUTC;
    int o  = r - bq*OUTC;
    float acc = bhead[o];
#pragma unroll
    for (int d = 0; d < HID; ++d) {
      float s = 0.f;
#pragma unroll
      for (int t = 0; t < TT; ++t) s += cnt_s[t][bq][d];
      acc = fmaf(s * (1.0f/(9216.0f*TT)), whead[d*OUTC + o], acc);
    }
    out[r] = acc;
  } else if (tid >= 192 && tid < 256) {
    // sr: wave 3 reduces all 256 counts (exact integers in fp32, any order)
    int i = tid - 192;
    const float* cf = &cnt_s[0][0][0];
    float s = cf[i] + cf[i + 64] + cf[i + 128] + cf[i + 192];
#pragma unroll
    for (int off = 1; off < 64; off <<= 1)
      s += __shfl_xor(s, off);
    if (i == 0) out[180] = s / DENOM;
  } else if (tid >= 256) {
    // smooth: wave 4 butterfly on its preloaded partial sums
#pragma unroll
    for (int off = 1; off < 64; off <<= 1)
      smacc += __shfl_xor(smacc, off);
    if (tid == 256) out[181] = smacc / DENOM;
  }
}

extern "C" void kernel_launch(void* const* d_in, const int* in_sizes, int n_in,
                              void* d_out, int out_size, void* d_ws, size_t ws_size,
                              hipStream_t stream)
{
  const float* x     = (const float*)d_in[0];
  const float* wproj = (const float*)d_in[1];
  const float* bproj = (const float*)d_in[2];
  const float* whead = (const float*)d_in[3];
  const float* bhead = (const float*)d_in[4];
  float* out = (float*)d_out;
  float* ws  = (float*)d_ws;

  dim3 grid(HH, BB);
  snn_main<<<grid, dim3(THREADS), 0, stream>>>(x, wproj, bproj, ws);
  snn_final<<<1, dim3(320), 0, stream>>>(ws, whead, bhead, out);
}